// Round 5
// baseline (786.057 us; speedup 1.0000x reference)
//
#include <hip/hip_runtime.h>
#include <hip/hip_bf16.h>
#include <hip/hip_fp16.h>

#define RN 4096
#define EN 131072
#define TN 1536
#define T2 768            // sample-pairs per row
#define SP 1040           // padded row stride in pairs (16B-aligned, > 1025)
#define PADP 257          // front wrap-replica pairs
#define PN 256
#define NBOUNCE 12
#define NCHUNK 4
#define CP 192            // pairs per chunk
// np.float32(np.log(1e-3))
#define LOG_GAMMA -6.90775528f
#define INV_SR (1.0f / 16000.0f)

// ---------------- CSR build ----------------

__global__ void hist_kernel(const int* __restrict__ row, int* __restrict__ cnt) {
    int e = blockIdx.x * blockDim.x + threadIdx.x;
    if (e < EN) atomicAdd(&cnt[row[e]], 1);
}

// single block, 1024 threads: exclusive scan of cnt[0..RN) -> off[0..RN], off[RN]=EN
__global__ void scan_kernel(const int* __restrict__ cnt, int* __restrict__ off,
                            int* __restrict__ cursor) {
    __shared__ int part[1024];
    int tid = threadIdx.x;
    int v0 = cnt[tid * 4 + 0], v1 = cnt[tid * 4 + 1];
    int v2 = cnt[tid * 4 + 2], v3 = cnt[tid * 4 + 3];
    part[tid] = v0 + v1 + v2 + v3;
    __syncthreads();
    for (int ofs = 1; ofs < 1024; ofs <<= 1) {
        int x = (tid >= ofs) ? part[tid - ofs] : 0;
        __syncthreads();
        part[tid] += x;
        __syncthreads();
    }
    int excl = (tid == 0) ? 0 : part[tid - 1];
    int o0 = excl, o1 = o0 + v0, o2 = o1 + v1, o3 = o2 + v2;
    off[tid * 4 + 0] = o0; cursor[tid * 4 + 0] = o0;
    off[tid * 4 + 1] = o1; cursor[tid * 4 + 1] = o1;
    off[tid * 4 + 2] = o2; cursor[tid * 4 + 2] = o2;
    off[tid * 4 + 3] = o3; cursor[tid * 4 + 3] = o3;
    if (tid == 1023) off[RN] = o3 + v3;
}

// per edge: kernel value + precomputed relative byte offset into the padded layout.
// md.x = ((col*SP + PADP - dpair) << 2) | (delay & 1),  md.y = bits(kern)
__global__ void scatter_kernel(const int* __restrict__ row, const int* __restrict__ col,
                               const int* __restrict__ rid, const int* __restrict__ delay,
                               const float* __restrict__ basis,
                               const float* __restrict__ absorption,
                               const float* __restrict__ scattering,
                               int* __restrict__ cursor, int2* __restrict__ mdarr) {
    int e = blockIdx.x * blockDim.x + threadIdx.x;
    if (e >= EN) return;
    int p = rid[e];
    float a = absorption[p];
    float s = scattering[p];
    float k = (1.0f - a) * (s * basis[e] + (1.0f - s) * basis[EN + e]);
    int d = delay[e];
    int dpair = (d + 1) >> 1;                       // d in [0,512)
    int off = ((col[e] * SP + PADP - dpair) << 2) | (d & 1);
    int pos = atomicAdd(&cursor[row[e]], 1);
    mdarr[pos] = make_int2(off, __float_as_int(k));
    if (e < 2) mdarr[EN + e] = make_int2(PADP << 2, 0);   // safe pad entries (k=0)
}

// ---------------- init: padded cur = tot = half(x * window) ----------------

__global__ __launch_bounds__(256) void init_kernel(const float* __restrict__ x,
                                                   __half* __restrict__ cur,
                                                   __half* __restrict__ tot) {
    int r = blockIdx.x;
    int tid = threadIdx.x;
    const float* xr = x + r * TN;
    uint* curp = (uint*)cur + (size_t)r * SP;
    uint* totp = (uint*)tot + (size_t)r * T2;
#pragma unroll
    for (int kk = 0; kk < 3; ++kk) {
        int q = tid + kk * 256;                     // pair index
        int t = q * 2;
        float wa = __expf(LOG_GAMMA * (float)t * INV_SR);
        float wb = __expf(LOG_GAMMA * (float)(t + 1) * INV_SR);
        __half2 h = __float22half2_rn(make_float2(xr[t] * wa, xr[t + 1] * wb));
        uint u = *(uint*)&h;
        curp[PADP + q] = u;
        if (q >= 511) curp[q - 511] = u;            // wrap replica
        totp[q] = u;
    }
}

// ---------------- bounce ----------------
// Block = 4 waves x 256 threads. Wave w of block (rg, chunk) handles row rg*4+w,
// output pairs [chunk*CP, chunk*CP+192), 3 pairs/lane. blockIdx = rg*4+chunk keeps
// chunk <-> XCD round-robin affinity. No barriers; waves fully independent.
// 2-edge software pipeline: edge j+1's 6 gather dwords are in flight while edge j
// is consumed. Unconditional 6-dword issue covers both delay parities.

#define ISSUE(mdv, W0, W1, W2, W3, W4, W5)                                        \
    {                                                                             \
        uint o_ = (uint)__builtin_amdgcn_readfirstlane((uint)(mdv).x);            \
        const uint* rp_ = (const uint*)(curb + (o_ & ~1u));                       \
        W0 = rp_[pb];       W1 = rp_[pb + 1];                                     \
        W2 = rp_[pb + 64];  W3 = rp_[pb + 65];                                    \
        W4 = rp_[pb + 128]; W5 = rp_[pb + 129];                                   \
    }

#define CONSUME(mdv, W0, W1, W2, W3, W4, W5)                                      \
    {                                                                             \
        uint mo_ = (uint)__builtin_amdgcn_readfirstlane((uint)(mdv).x);           \
        float k_ = __uint_as_float(                                               \
            (uint)__builtin_amdgcn_readfirstlane((uint)(mdv).y));                 \
        bool odd_ = (mo_ & 1u) != 0u;                                             \
        uint v0_ = odd_ ? __builtin_amdgcn_alignbit(W1, W0, 16) : W0;             \
        uint v1_ = odd_ ? __builtin_amdgcn_alignbit(W3, W2, 16) : W2;             \
        uint v2_ = odd_ ? __builtin_amdgcn_alignbit(W5, W4, 16) : W4;             \
        __half2 h0_ = *(__half2*)&v0_, h1_ = *(__half2*)&v1_, h2_ = *(__half2*)&v2_; \
        a0 = fmaf(k_, __half2float(h0_.x), a0);                                   \
        a1 = fmaf(k_, __half2float(h0_.y), a1);                                   \
        a2 = fmaf(k_, __half2float(h1_.x), a2);                                   \
        a3 = fmaf(k_, __half2float(h1_.y), a3);                                   \
        a4 = fmaf(k_, __half2float(h2_.x), a4);                                   \
        a5 = fmaf(k_, __half2float(h2_.y), a5);                                   \
    }

__global__ __launch_bounds__(256) void bounce_kernel(
        const __half* __restrict__ cur, __half* __restrict__ nxt, __half* __restrict__ tot,
        const int* __restrict__ offs, const int2* __restrict__ mdarr) {
    int bid = blockIdx.x;
    int rg = bid >> 2;
    int c0 = (bid & 3) * CP;
    int wave = threadIdx.x >> 6;
    int lane = threadIdx.x & 63;
    int r = rg * 4 + wave;
    int pb = c0 + lane;                             // base pair index (loop-invariant)
    int e0 = __builtin_amdgcn_readfirstlane(offs[r]);
    int e1 = __builtin_amdgcn_readfirstlane(offs[r + 1]);
    float a0 = 0.f, a1 = 0.f, a2 = 0.f, a3 = 0.f, a4 = 0.f, a5 = 0.f;
    const char* curb = (const char*)cur;

    uint A0, A1, A2, A3, A4, A5, B0, B1, B2, B3, B4, B5;
    int2 mdA = mdarr[e0];
    int2 mdB = mdarr[e0 + 1];
    ISSUE(mdA, A0, A1, A2, A3, A4, A5);
    for (int j = e0; j < e1; j += 2) {
        int2 mdC = mdarr[j + 2];                    // may overrun into pads (safe)
        ISSUE(mdB, B0, B1, B2, B3, B4, B5);         // edge j+1 (overrun-issue safe)
        CONSUME(mdA, A0, A1, A2, A3, A4, A5);       // edge j
        if (j + 1 >= e1) break;
        int2 mdD = mdarr[j + 3];
        ISSUE(mdC, A0, A1, A2, A3, A4, A5);         // edge j+2 (overrun-issue safe)
        CONSUME(mdB, B0, B1, B2, B3, B4, B5);       // edge j+1
        mdA = mdC; mdB = mdD;
    }

    uint* nxtp = (uint*)nxt + (size_t)r * SP;
    uint* totp = (uint*)tot + (size_t)r * T2;
    float ax[3] = {a0, a2, a4}, ay[3] = {a1, a3, a5};
#pragma unroll
    for (int kk = 0; kk < 3; ++kk) {
        int q = pb + kk * 64;
        __half2 h = __float22half2_rn(make_float2(ax[kk], ay[kk]));
        uint u = *(uint*)&h;
        nxtp[PADP + q] = u;
        if (q >= 511) nxtp[q - 511] = u;            // wrap replica
        uint tu = totp[q];
        __half2 tn = __hadd2(*(__half2*)&tu, h);
        totp[q] = *(uint*)&tn;
    }
}

// ---------------- detection ----------------

__global__ void detect_kernel(const __half* __restrict__ tot, const float* __restrict__ w,
                              const int* __restrict__ dd, float* __restrict__ det) {
    int t = blockIdx.x * 256 + threadIdx.x;
    int r0 = blockIdx.y * 64;
    float acc = 0.f;
    for (int r = r0; r < r0 + 64; ++r) {
        int d = dd[r];
        int idx = t - d;
        if (idx < 0) idx += TN;
        acc = fmaf(w[r], __half2float(tot[r * TN + idx]), acc);
    }
    atomicAdd(&det[t], acc);
}

__global__ void final_kernel(const float* __restrict__ det, float* __restrict__ out) {
    int t = blockIdx.x * 256 + threadIdx.x;
    if (t < TN) out[t] = det[t] * __expf(-LOG_GAMMA * (float)t * INV_SR);
}

// ---------------- launch ----------------

extern "C" void kernel_launch(void* const* d_in, const int* in_sizes, int n_in,
                              void* d_out, int out_size, void* d_ws, size_t ws_size,
                              hipStream_t stream) {
    const float* init_rad   = (const float*)d_in[0];
    const float* basis      = (const float*)d_in[1];
    const float* absorption = (const float*)d_in[2];
    const float* scattering = (const float*)d_in[3];
    const float* det_w      = (const float*)d_in[4];
    const int*   row        = (const int*)d_in[5];
    const int*   col        = (const int*)d_in[6];
    const int*   rid        = (const int*)d_in[7];
    const int*   delay      = (const int*)d_in[8];
    const int*   det_delay  = (const int*)d_in[9];
    float* out = (float*)d_out;

    char* ws = (char*)d_ws;
    size_t o = 0;
    auto alloc = [&](size_t bytes) {
        void* p = ws + o;
        o = (o + bytes + 255) & ~(size_t)255;
        return p;
    };
    int*    cnt    = (int*)alloc(RN * 4);
    int*    off    = (int*)alloc((RN + 1) * 4);
    int*    cursor = (int*)alloc(RN * 4);
    int2*   mdarr  = (int2*)alloc((size_t)(EN + 2) * 8);
    __half* bufA   = (__half*)alloc((size_t)RN * SP * 4);
    __half* bufB   = (__half*)alloc((size_t)RN * SP * 4);
    __half* tot    = (__half*)alloc((size_t)RN * T2 * 4);
    float*  det    = (float*)alloc(TN * 4);

    hipMemsetAsync(cnt, 0, RN * 4, stream);
    hipMemsetAsync(det, 0, TN * 4, stream);

    hist_kernel<<<EN / 256, 256, 0, stream>>>(row, cnt);
    scan_kernel<<<1, 1024, 0, stream>>>(cnt, off, cursor);
    scatter_kernel<<<EN / 256, 256, 0, stream>>>(row, col, rid, delay, basis,
                                                 absorption, scattering, cursor, mdarr);
    init_kernel<<<RN, 256, 0, stream>>>(init_rad, bufA, tot);

    __half* cur = bufA;
    __half* nxt = bufB;
    for (int b = 0; b < NBOUNCE; ++b) {
        bounce_kernel<<<(RN / 4) * NCHUNK, 256, 0, stream>>>(cur, nxt, tot, off, mdarr);
        __half* tmp = cur; cur = nxt; nxt = tmp;
    }

    detect_kernel<<<dim3(TN / 256, RN / 64), 256, 0, stream>>>(tot, det_w, det_delay, det);
    final_kernel<<<TN / 256, 256, 0, stream>>>(det, out);
}